// Round 13
// baseline (1069.002 us; speedup 1.0000x reference)
//
#include <hip/hip_runtime.h>
#include <math.h>

typedef _Float16 half8 __attribute__((ext_vector_type(8)));
typedef _Float16 half2t __attribute__((ext_vector_type(2)));
typedef float floatx4 __attribute__((ext_vector_type(4)));

static __device__ __forceinline__ unsigned f2o(float f) {
  unsigned b = __float_as_uint(f);
  return (b & 0x80000000u) ? ~b : (b | 0x80000000u);
}
static __device__ __forceinline__ float o2f(unsigned u) {
  return __uint_as_float((u & 0x80000000u) ? (u & 0x7fffffffu) : ~u);
}
static __device__ __forceinline__ unsigned pack2(float a, float b) {
  _Float16 ha = (_Float16)a, hb = (_Float16)b;
  unsigned short ua = __builtin_bit_cast(unsigned short, ha);
  unsigned short ub = __builtin_bit_cast(unsigned short, hb);
  return (unsigned)ua | ((unsigned)ub << 16);
}
static __device__ __forceinline__ float dot2acc(unsigned x, unsigned w, float acc) {
  half2t xh = __builtin_bit_cast(half2t, x);
  half2t wh = __builtin_bit_cast(half2t, w);
#if __has_builtin(__builtin_amdgcn_fdot2)
  return __builtin_amdgcn_fdot2(xh, wh, acc, false);
#else
  return fmaf((float)xh[0], (float)wh[0], fmaf((float)xh[1], (float)wh[1], acc));
#endif
}

__global__ void nc_zero_u32(unsigned* __restrict__ p, int n) {
  int i = blockIdx.x * blockDim.x + threadIdx.x;
  if (i < n) p[i] = 0u;
}

// ---------- prep: cast f32 [c][pos] -> f16 transposed [pos][c] ----------
__global__ __launch_bounds__(256) void nc_prep(const float* __restrict__ fA,
                                               const float* __restrict__ fB,
                                               unsigned short* __restrict__ fAt,
                                               unsigned short* __restrict__ fBt) {
  __shared__ float tile[64][65];
  int pt = blockIdx.x, ct = blockIdx.y, z = blockIdx.z;
  int b = z & 3, f = z >> 2;
  const float* src = (f ? fB : fA) + ((size_t)b << 20);
  unsigned short* dst = (f ? fBt : fAt) + ((size_t)b << 20);
  int p0 = pt << 6, c0 = ct << 6;
  int tid = threadIdx.x;
  int pcol = tid & 63, crow4 = tid >> 6;
#pragma unroll
  for (int it = 0; it < 16; ++it) {
    int c = (it << 2) + crow4;
    tile[c][pcol] = src[((size_t)(c0 + c) << 10) + p0 + pcol];
  }
  __syncthreads();
#pragma unroll
  for (int pass = 0; pass < 2; ++pass) {
    int u = tid + (pass << 8);
    int pr = u >> 3, c8 = (u & 7) << 3;
    unsigned short h[8];
#pragma unroll
    for (int e = 0; e < 8; ++e) {
      _Float16 v = (_Float16)tile[c8 + e][pr];
      h[e] = __builtin_bit_cast(unsigned short, v);
    }
    uint4 w;
    w.x = (unsigned)h[0] | ((unsigned)h[1] << 16);
    w.y = (unsigned)h[2] | ((unsigned)h[3] << 16);
    w.z = (unsigned)h[4] | ((unsigned)h[5] << 16);
    w.w = (unsigned)h[6] | ((unsigned)h[7] << 16);
    *(uint4*)&dst[((size_t)(p0 + pr) << 10) + c0 + c8] = w;
  }
}

// ---------- norm^2 per position ----------
__global__ __launch_bounds__(256) void nc_norms16(const unsigned short* __restrict__ fAt,
                                                  const unsigned short* __restrict__ fBt,
                                                  float* __restrict__ nsqA,
                                                  float* __restrict__ nsqB) {
  int b = blockIdx.y, f = blockIdx.z;
  const unsigned short* src = (f ? fBt : fAt) + ((size_t)b << 20);
  float* nsq = (f ? nsqB : nsqA) + (b << 10);
  int tid = threadIdx.x;
  int g = tid & 3, pos = (blockIdx.x << 6) + (tid >> 2);
  const unsigned short* row = src + ((size_t)pos << 10) + (g << 3);
  float s = 0.f;
#pragma unroll
  for (int i = 0; i < 32; ++i) {
    uint4 v = *(const uint4*)(row + (i << 5));
    const unsigned short* hp = (const unsigned short*)&v;
#pragma unroll
    for (int e = 0; e < 8; ++e) {
      float x = (float)__builtin_bit_cast(_Float16, hp[e]);
      s = fmaf(x, x, s);
    }
  }
  s += __shfl_xor(s, 1);
  s += __shfl_xor(s, 2);
  if (g == 0) nsq[pos] = s;
}

// ---------- correlation GEMM + fused row/col max ----------
__global__ __launch_bounds__(256) void nc_gemm16(
    const unsigned short* __restrict__ fAt, const unsigned short* __restrict__ fBt,
    const float* __restrict__ nsqA, const float* __restrict__ nsqB,
    float* __restrict__ C, unsigned* __restrict__ maxA1u, unsigned* __restrict__ maxBu1) {
  __shared__ unsigned short Ald[64 * 72];
  __shared__ unsigned short Bld[64 * 72];
  int q0 = blockIdx.x << 6, p0 = blockIdx.y << 6, b = blockIdx.z;
  const unsigned short* Ab = fAt + ((size_t)b << 20);
  const unsigned short* Bb = fBt + ((size_t)b << 20);
  int tid = threadIdx.x;
  int lane = tid & 63, w = tid >> 6;
  int ncol = lane & 15, g4 = lane >> 4;
  floatx4 acc[4];
#pragma unroll
  for (int t = 0; t < 4; ++t) acc[t] = (floatx4){0.f, 0.f, 0.f, 0.f};

  for (int k0 = 0; k0 < 1024; k0 += 64) {
    __syncthreads();
#pragma unroll
    for (int pass = 0; pass < 2; ++pass) {
      int u = tid + (pass << 8);
      int pr = u >> 3, c8 = (u & 7) << 3;
      *(uint4*)&Ald[pr * 72 + c8] = *(const uint4*)&Ab[((size_t)(p0 + pr) << 10) + k0 + c8];
      *(uint4*)&Bld[pr * 72 + c8] = *(const uint4*)&Bb[((size_t)(q0 + pr) << 10) + k0 + c8];
    }
    __syncthreads();
#pragma unroll
    for (int ch = 0; ch < 2; ++ch) {
      half8 af = *(const half8*)&Ald[(w * 16 + ncol) * 72 + (ch << 5) + (g4 << 3)];
#pragma unroll
      for (int t = 0; t < 4; ++t) {
        half8 bf = *(const half8*)&Bld[(t * 16 + ncol) * 72 + (ch << 5) + (g4 << 3)];
        acc[t] = __builtin_amdgcn_mfma_f32_16x16x32_f16(af, bf, acc[t], 0, 0, 0);
      }
    }
  }

  float na[4], nb[4];
#pragma unroll
  for (int r = 0; r < 4; ++r) na[r] = nsqA[(b << 10) + p0 + w * 16 + (g4 << 2) + r] + 1e-6f;
#pragma unroll
  for (int t = 0; t < 4; ++t) nb[t] = nsqB[(b << 10) + q0 + t * 16 + ncol] + 1e-6f;

  float rm[4] = {-INFINITY, -INFINITY, -INFINITY, -INFINITY};
  float cm[4];
#pragma unroll
  for (int t = 0; t < 4; ++t) {
    float colm = -INFINITY;
#pragma unroll
    for (int r = 0; r < 4; ++r) {
      float val = acc[t][r] * rsqrtf(na[r] * nb[t]);
      size_t o = ((size_t)b << 20) + ((size_t)(p0 + w * 16 + (g4 << 2) + r) << 10) +
                 q0 + t * 16 + ncol;
      C[o] = val;
      rm[r] = fmaxf(rm[r], val);
      colm = fmaxf(colm, val);
    }
    cm[t] = colm;
  }
#pragma unroll
  for (int d = 1; d <= 8; d <<= 1)
#pragma unroll
    for (int r = 0; r < 4; ++r) rm[r] = fmaxf(rm[r], __shfl_xor(rm[r], d));
  if (ncol == 0) {
#pragma unroll
    for (int r = 0; r < 4; ++r)
      atomicMax(&maxA1u[(b << 10) + p0 + w * 16 + (g4 << 2) + r], f2o(rm[r]));
  }
#pragma unroll
  for (int d = 16; d <= 32; d <<= 1)
#pragma unroll
    for (int t = 0; t < 4; ++t) cm[t] = fmaxf(cm[t], __shfl_xor(cm[t], d));
  if (g4 == 0) {
#pragma unroll
    for (int t = 0; t < 4; ++t)
      atomicMax(&maxBu1[(b << 10) + q0 + t * 16 + ncol], f2o(cm[t]));
  }
}

// ---------- row / col max (fp32, final pass) ----------
__global__ __launch_bounds__(256) void nc_rowmax(const float* __restrict__ X,
                                                 float* __restrict__ rmax) {
  int row = blockIdx.x;
  const float* x = X + ((size_t)row << 10);
  int tid = threadIdx.x;
  float m = fmaxf(fmaxf(x[tid], x[tid + 256]), fmaxf(x[tid + 512], x[tid + 768]));
  __shared__ float red[256];
  red[tid] = m;
  __syncthreads();
  for (int s = 128; s > 0; s >>= 1) {
    if (tid < s) red[tid] = fmaxf(red[tid], red[tid + s]);
    __syncthreads();
  }
  if (tid == 0) rmax[row] = red[0];
}

__global__ __launch_bounds__(256) void nc_colmax(const float* __restrict__ X,
                                                 unsigned* __restrict__ cmaxu) {
  int b = blockIdx.z;
  int q = (blockIdx.x << 8) + threadIdx.x;
  int p0 = blockIdx.y << 4;
  const float* x = X + ((size_t)b << 20) + ((size_t)p0 << 10) + q;
  float m = -INFINITY;
#pragma unroll
  for (int r = 0; r < 16; ++r) m = fmaxf(m, x[(size_t)r << 10]);
  atomicMax(&cmaxu[(b << 10) + q], f2o(m));
}

// ---------- mutual matching ----------
__global__ __launch_bounds__(256) void nc_mm_f32(const float* __restrict__ X,
                                                 const float* __restrict__ rmax,
                                                 const unsigned* __restrict__ cmaxu,
                                                 float* __restrict__ Y) {
  size_t i4 = (size_t)blockIdx.x * 256 + threadIdx.x;
  size_t base = i4 << 2;
  float4 x = *(const float4*)&X[base];
  float ma = rmax[base >> 10] + 1e-5f;
  const unsigned* cm = &cmaxu[((base >> 20) << 10) + (base & 1023)];
  float4 y;
  y.x = x.x * x.x * x.x / (ma * (o2f(cm[0]) + 1e-5f));
  y.y = x.y * x.y * x.y / (ma * (o2f(cm[1]) + 1e-5f));
  y.z = x.z * x.z * x.z / (ma * (o2f(cm[2]) + 1e-5f));
  y.w = x.w * x.w * x.w / (ma * (o2f(cm[3]) + 1e-5f));
  *(float4*)&Y[base] = y;
}

__global__ __launch_bounds__(256) void nc_mm_f16(const float* __restrict__ X,
                                                 const unsigned* __restrict__ rmaxu,
                                                 const unsigned* __restrict__ cmaxu,
                                                 unsigned short* __restrict__ Y16) {
  size_t i4 = (size_t)blockIdx.x * 256 + threadIdx.x;
  size_t base = i4 << 2;
  float4 x = *(const float4*)&X[base];
  float ma = o2f(rmaxu[base >> 10]) + 1e-5f;
  const unsigned* cm = &cmaxu[((base >> 20) << 10) + (base & 1023)];
  float y0 = x.x * x.x * x.x / (ma * (o2f(cm[0]) + 1e-5f));
  float y1 = x.y * x.y * x.y / (ma * (o2f(cm[1]) + 1e-5f));
  float y2 = x.z * x.z * x.z / (ma * (o2f(cm[2]) + 1e-5f));
  float y3 = x.w * x.w * x.w / (ma * (o2f(cm[3]) + 1e-5f));
  unsigned* dst = (unsigned*)&Y16[base];
  dst[0] = pack2(y0, y1);
  dst[1] = pack2(y2, y3);
}

// ---------- weight prepack ----------
__global__ void nc_wpack(const float* __restrict__ W1, const float* __restrict__ W2,
                         const float* __restrict__ W3,
                         unsigned short* __restrict__ Wf, unsigned* __restrict__ w3p) {
  int f = blockIdx.x;
  int t = threadIdx.x;
  if (f < 72) {
    int v, chunk, tap, CI;
    const float* W;
    if (f < 18) { v = f / 9; tap = f % 9; chunk = 0; CI = 1; W = W1; }
    else { int g = f - 18; v = g / 27; g %= 27; chunk = g / 9; tap = g % 9; CI = 10; W = W2; }
    for (int e = t; e < 512; e += 256) {
      int lane = e >> 3, j = e & 7;
      int co = lane & 15;
      int k = ((lane >> 4) << 3) + j;
      int cip = chunk * 32 + k;
      float val = 0.f;
      if (co < 10 && cip < CI * 9) {
        int ci = cip / 9, r = cip % 9;
        int widx = v ? (tap * 9 + r) : (r * 9 + tap);
        val = W[(co * CI + ci) * 81 + widx];
      }
      _Float16 h = (_Float16)val;
      Wf[f * 512 + e] = __builtin_bit_cast(unsigned short, h);
    }
  } else {
    for (int e = t; e < 2 * 5 * 81; e += 256) {
      int v = e / 405;
      int rem = e - v * 405;
      int p = rem / 81;
      int t81 = rem - p * 81;
      int r = t81 / 9, ab = t81 - r * 9;
      int widx = v ? (ab * 9 + r) : (r * 9 + ab);
      w3p[e] = pack2(W3[(2 * p) * 81 + widx], W3[(2 * p + 1) * 81 + widx]);
    }
  }
}

// ---------- conv1, both branches; grid (1024, 4, NB) ----------
__global__ __launch_bounds__(256, 5) void nc_conv1ab_k(
    const unsigned short* __restrict__ xin, const unsigned short* __restrict__ Wf,
    const float* __restrict__ bias, unsigned short* __restrict__ t1A,
    unsigned short* __restrict__ t1B, int b_base) {
  __shared__ unsigned short xs[360 * 40];
  int bx = blockIdx.x, qt = blockIdx.y;
  int bl = blockIdx.z;
  int b = b_base + bl;
  unsigned short* t1Ab = t1A + ((size_t)bl * 10 << 20);
  unsigned short* t1Bb = t1B + ((size_t)bl * 10 << 20);
  int ij = ((bx & 7) << 7) + (bx >> 3);
  int i = ij >> 5, j = ij & 31;
  int tid = threadIdx.x;
  int lane = tid & 63, w = tid >> 6;
  int ncol = lane & 15, g4 = lane >> 4;
  int kp = tid & 15, colg = (tid >> 4) & 7, rowb = tid >> 7;

  if (tid < 80) {
    int rr = tid >> 3;
    int e = tid & 7;
    int pos = rr * 36 + ((e >> 2) ? 33 : 0);
    half8 z = {};
    *(half8*)((char*)xs + pos * 80 + (e & 3) * 16) = z;
  }

  int rbase[4];
#pragma unroll
  for (int q = 0; q < 4; ++q) {
    int n0 = (((w << 2) + q) << 4);
    rbase[q] = ((n0 >> 5) * 36 + (n0 & 31) + ncol) * 80 + (g4 << 4);
  }

  const unsigned short* p0 = nullptr;
  const unsigned short* p1 = nullptr;
  {
    int cip0 = kp << 1;
    if (cip0 < 9) {
      int ii = i + cip0 / 3 - 1, jj = j + cip0 % 3 - 1;
      if ((unsigned)ii < 32u && (unsigned)jj < 32u)
        p0 = xin + ((size_t)b << 20) + ((ii * 32 + jj) << 10);
    }
    int cip1 = cip0 + 1;
    if (cip1 < 9) {
      int ii = i + cip1 / 3 - 1, jj = j + cip1 % 3 - 1;
      if ((unsigned)ii < 32u && (unsigned)jj < 32u)
        p1 = xin + ((size_t)b << 20) + ((ii * 32 + jj) << 10);
    }
  }
  ushort4 a0[5], a1[5];
#pragma unroll
  for (int it = 0; it < 5; ++it) {
    int row_g = (qt << 3) - 1 + rowb + 2 * it;
    bool rv = (unsigned)row_g < 32u;
    int goff = (row_g << 5) + (colg << 2);
    ushort4 z = {0, 0, 0, 0};
    a0[it] = z; a1[it] = z;
    if (rv && p0) a0[it] = *(const ushort4*)(p0 + goff);
    if (rv && p1) a1[it] = *(const ushort4*)(p1 + goff);
  }
  __syncthreads();
#pragma unroll
  for (int it = 0; it < 5; ++it) {
    int row = rowb + 2 * it;
    unsigned* dstw = (unsigned*)xs + (row * 36 + 1 + (colg << 2)) * 20 + kp;
    dstw[0]  = (unsigned)a0[it].x | ((unsigned)a1[it].x << 16);
    dstw[20] = (unsigned)a0[it].y | ((unsigned)a1[it].y << 16);
    dstw[40] = (unsigned)a0[it].z | ((unsigned)a1[it].z << 16);
    dstw[60] = (unsigned)a0[it].w | ((unsigned)a1[it].w << 16);
  }
  __syncthreads();

  floatx4 accA[4], accB[4];
#pragma unroll
  for (int q = 0; q < 4; ++q) {
    accA[q] = (floatx4){0.f, 0.f, 0.f, 0.f};
    accB[q] = (floatx4){0.f, 0.f, 0.f, 0.f};
  }
  const unsigned short* wfp = Wf + (lane << 3);
#pragma unroll
  for (int tap = 0; tap < 9; ++tap) {
    half8 afA = *(const half8*)(wfp + tap * 512);
    half8 afB = *(const half8*)(wfp + (9 + tap) * 512);
    const int off = ((tap / 3) * 36 + (tap % 3)) * 80;
#pragma unroll
    for (int q = 0; q < 4; ++q) {
      half8 bv = *(const half8*)((const char*)xs + rbase[q] + off);
      accA[q] = __builtin_amdgcn_mfma_f32_16x16x32_f16(afA, bv, accA[q], 0, 0, 0);
      accB[q] = __builtin_amdgcn_mfma_f32_16x16x32_f16(afB, bv, accB[q], 0, 0, 0);
    }
  }

#pragma unroll
  for (int q = 0; q < 4; ++q) {
    int ng = (qt << 8) + (((w << 2) + q) << 4) + ncol;
#pragma unroll
    for (int r = 0; r < 4; ++r) {
      int co = (g4 << 2) + r;
      if (co < 10) {
        size_t oidx = ((size_t)co << 20) + ((size_t)ij << 10) + ng;
        float vA = fmaxf(accA[q][r] + bias[co], 0.f);
        float vB = fmaxf(accB[q][r] + bias[co], 0.f);
        _Float16 hA = (_Float16)vA, hB = (_Float16)vB;
        t1Ab[oidx] = __builtin_bit_cast(unsigned short, hA);
        t1Bb[oidx] = __builtin_bit_cast(unsigned short, hB);
      }
    }
  }
}

// ---------- conv2 (10->10), 512 threads (100% occupancy: 4 blk/CU x 8 waves);
// grid (1024, 4, 2*NB): z = branch | batch<<1. Wave w owns local row w
// (2 q-halves of 16 pos); staging = 1280 jobs = 16kp x 8colg x 10rows over
// 512 threads x 3 row-units (row<10 guard). ----------
__global__ __launch_bounds__(512, 8) void nc_conv2ab_k(
    const unsigned short* __restrict__ t1A, const unsigned short* __restrict__ t1B,
    const unsigned short* __restrict__ Wf, const float* __restrict__ bias,
    unsigned* __restrict__ t2pA, unsigned* __restrict__ t2pB) {
  constexpr int NCH = 3;
  __shared__ unsigned short xs[360 * 40];
  int z = blockIdx.z;
  int br = z & 1, bl = z >> 1;
  const unsigned short* xin = (br ? t1B : t1A) + ((size_t)bl * 10 << 20);
  const unsigned short* Wfz = Wf + (size_t)(18 + br * 27) * 512;
  unsigned* t2p = (br ? t2pB : t2pA) + ((size_t)bl * 5 << 20);
  int bx = blockIdx.x, qt = blockIdx.y;
  int ij = ((bx & 7) << 7) + (bx >> 3);
  int i = ij >> 5, j = ij & 31;
  int tid = threadIdx.x;
  int lane = tid & 63, w = tid >> 6;
  int ncol = lane & 15, g4 = lane >> 4;
  int kp = tid & 15, colg = (tid >> 4) & 7, rowb = tid >> 7;  // rowb 0..3

  if (tid < 80) {
    int rr = tid >> 3;
    int e = tid & 7;
    int pos = rr * 36 + ((e >> 2) ? 33 : 0);
    half8 zz = {};
    *(half8*)((char*)xs + pos * 80 + (e & 3) * 16) = zz;
  }

  int rbase[2];
#pragma unroll
  for (int q = 0; q < 2; ++q) {
    int n0 = (((w << 1) + q) << 4);
    rbase[q] = ((n0 >> 5) * 36 + (n0 & 31) + ncol) * 80 + (g4 << 4);
  }

  floatx4 acc[2];
#pragma unroll
  for (int q = 0; q < 2; ++q) acc[q] = (floatx4){0.f, 0.f, 0.f, 0.f};

  ushort4 a0[3], a1[3];
  auto PREF = [&](int ch) {
    int cip0 = (ch << 5) + (kp << 1);
    const unsigned short* p0 = nullptr;
    const unsigned short* p1 = nullptr;
    if (cip0 < 90) {
      int ci = cip0 / 9, r9 = cip0 - ci * 9;
      int ii = i + r9 / 3 - 1, jj = j + r9 % 3 - 1;
      if ((unsigned)ii < 32u && (unsigned)jj < 32u)
        p0 = xin + ((size_t)ci << 20) + ((ii * 32 + jj) << 10);
    }
    int cip1 = cip0 + 1;
    if (cip1 < 90) {
      int ci = cip1 / 9, r9 = cip1 - ci * 9;
      int ii = i + r9 / 3 - 1, jj = j + r9 % 3 - 1;
      if ((unsigned)ii < 32u && (unsigned)jj < 32u)
        p1 = xin + ((size_t)ci << 20) + ((ii * 32 + jj) << 10);
    }
#pragma unroll
    for (int u = 0; u < 3; ++u) {
      int row = rowb + (u << 2);
      int row_g = (qt << 3) - 1 + row;
      bool rv = (row < 10) && ((unsigned)row_g < 32u);
      int goff = (row_g << 5) + (colg << 2);
      ushort4 zv = {0, 0, 0, 0};
      a0[u] = zv; a1[u] = zv;
      if (rv && p0) a0[u] = *(const ushort4*)(p0 + goff);
      if (rv && p1) a1[u] = *(const ushort4*)(p1 + goff);
    }
  };

  PREF(0);
  for (int ch = 0; ch < NCH; ++ch) {
    __syncthreads();  // prior chunk's reads done before overwrite
#pragma unroll
    for (int u = 0; u < 3; ++u) {
      int row = rowb + (u << 2);
      if (row < 10) {
        unsigned* dstw = (unsigned*)xs + (row * 36 + 1 + (colg << 2)) * 20 + kp;
        dstw[0]  = (unsigned)a0[u].x | ((unsigned)a1[u].x << 16);
        dstw[20] = (unsigned)a0[u].y | ((unsigned)a1[u].y << 16);
        dstw[40] = (unsigned)a0[u].z | ((unsigned)a1[u].z << 16);
        dstw[60] = (unsigned)a0[u].w | ((unsigned)a1[u].w << 16);
      }
    }
    __syncthreads();
    if (ch + 1 < NCH) PREF(ch + 1);  // loads in flight across the MFMA phase

    const unsigned short* wfp = Wfz + (size_t)(ch * 9) * 512 + (lane << 3);
#pragma unroll
    for (int tap = 0; tap < 9; ++tap) {
      half8 af = *(const half8*)(wfp + tap * 512);
      const int off = ((tap / 3) * 36 + (tap % 3)) * 80;
#pragma unroll
      for (int q = 0; q < 2; ++q) {
        half8 bv = *(const half8*)((const char*)xs + rbase[q] + off);
        acc[q] = __builtin_amdgcn_mfma_f32_16x16x32_f16(af, bv, acc[q], 0, 0, 0);
      }
    }
  }

#pragma unroll
  for (int q = 0; q < 2; ++q) {
    int ng = (qt << 8) + (((w << 1) + q) << 4) + ncol;
    int c0 = g4 << 2;
    float v0 = fmaxf(acc[q][0] + (c0 + 0 < 10 ? bias[c0 + 0] : 0.f), 0.f);
    float v1 = fmaxf(acc[q][1] + (c0 + 1 < 10 ? bias[c0 + 1] : 0.f), 0.f);
    float v2 = fmaxf(acc[q][2] + (c0 + 2 < 10 ? bias[c0 + 2] : 0.f), 0.f);
    float v3 = fmaxf(acc[q][3] + (c0 + 3 < 10 ? bias[c0 + 3] : 0.f), 0.f);
    int p0 = g4 << 1;
    if (p0 < 5)
      t2p[((size_t)p0 << 20) + ((size_t)ij << 10) + ng] = pack2(v0, v1);
    if (p0 + 1 < 5)
      t2p[((size_t)(p0 + 1) << 20) + ((size_t)ij << 10) + ng] = pack2(v2, v3);
  }
}

// ---------- conv3 (10->1), DPP halo exchange; grid (1024, NB) ----------
template <bool ACCUM>
static __device__ __forceinline__ void nc_conv3_body(
    const unsigned* __restrict__ t2p, const unsigned* __restrict__ w3p,
    const float* __restrict__ b3, float* __restrict__ yout, int b_base) {
  __shared__ unsigned xs2[5][33 * 32];
  int bx = blockIdx.x;
  int bl = blockIdx.y;
  int b = b_base + bl;
  const unsigned* t2b = t2p + ((size_t)bl * 5 << 20);
  int ij = ((bx & 7) << 7) + (bx >> 3);
  int i = ij >> 5, j = ij & 31;
  int tid = threadIdx.x;
  int k = tid >> 3, l4 = (tid & 7) << 2;
  float acc[4] = {0.f, 0.f, 0.f, 0.f};

  for (int di = -1; di <= 1; ++di) {
    int ii = i + di;
    for (int dj = -1; dj <= 1; ++dj) {
      int jj = j + dj;
      bool pv = ((unsigned)ii < 32u) && ((unsigned)jj < 32u);
      if (!pv) continue;
      __syncthreads();
#pragma unroll
      for (int p = 0; p < 5; ++p) {
#pragma unroll
        for (int s = 0; s < 4; ++s) {
          int pos = (s << 8) + tid;
          unsigned v = t2b[((size_t)p << 20) + ((size_t)(ii * 32 + jj) << 10) + pos];
          xs2[p][(pos >> 5) * 33 + (pos & 31)] = v;
        }
      }
      __syncthreads();
      int r9 = (di + 1) * 3 + (dj + 1);
#pragma unroll
      for (int p = 0; p < 5; ++p) {
        unsigned vv[3][6];
#pragma unroll
        for (int a = 0; a < 3; ++a) {
          int rr = k + a - 1;
          bool rv = (unsigned)rr < 32u;
          unsigned c0 = rv ? xs2[p][rr * 33 + l4 + 0] : 0u;
          unsigned c1 = rv ? xs2[p][rr * 33 + l4 + 1] : 0u;
          unsigned c2 = rv ? xs2[p][rr * 33 + l4 + 2] : 0u;
          unsigned c3 = rv ? xs2[p][rr * 33 + l4 + 3] : 0u;
          int Ld = __builtin_amdgcn_update_dpp(0, (int)c3, 0x111, 0xf, 0xf, true);
          int Rd = __builtin_amdgcn_update_dpp(0, (int)c0, 0x101, 0xf, 0xf, true);
          vv[a][0] = (l4 == 0) ? 0u : (unsigned)Ld;
          vv[a][1] = c0; vv[a][2] = c1; vv[a][3] = c2; vv[a][4] = c3;
          vv[a][5] = (l4 == 28) ? 0u : (unsigned)Rd;
        }
#pragma unroll
        for (int a = 0; a < 3; ++a)
#pragma unroll
          for (int bc = 0; bc < 3; ++bc) {
            unsigned wp = w3p[p * 81 + r9 * 9 + a * 3 + bc];
#pragma unroll
            for (int r = 0; r < 4; ++r) acc[r] = dot2acc(vv[a][r + bc], wp, acc[r]);
          }
      }
    }
  }
  float bb = b3[0];
  size_t o = ((size_t)b << 20) + ((size_t)ij << 10) + (k << 5) + l4;
  float4 out4;
  out4.x = fmaxf(acc[0] + bb, 0.f);
  out4.y = fmaxf(acc[1] + bb, 0.f);
  out4.z = fmaxf(acc[2] + bb, 0.f);
  out4.w = fmaxf(acc[3] + bb, 0.f);
  if (ACCUM) {
    float4 prev = *(const float4*)&yout[o];
    out4.x += prev.x; out4.y += prev.y; out4.z += prev.z; out4.w += prev.w;
  }
  *(float4*)&yout[o] = out4;
}

__global__ __launch_bounds__(256) void nc_conv3a(
    const unsigned* __restrict__ t2p, const unsigned* __restrict__ w3p,
    const float* __restrict__ b3, float* __restrict__ yout, int b_base) {
  nc_conv3_body<false>(t2p, w3p, b3, yout, b_base);
}
__global__ __launch_bounds__(256) void nc_conv3b(
    const unsigned* __restrict__ t2p, const unsigned* __restrict__ w3p,
    const float* __restrict__ b3, float* __restrict__ yout, int b_base) {
  nc_conv3_body<true>(t2p, w3p, b3, yout, b_base);
}

extern "C" void kernel_launch(void* const* d_in, const int* in_sizes, int n_in,
                              void* d_out, int out_size, void* d_ws, size_t ws_size,
                              hipStream_t stream) {
  const float* fA = (const float*)d_in[0];
  const float* fB = (const float*)d_in[1];
  const float* W1 = (const float*)d_in[2];
  const float* b1 = (const float*)d_in[3];
  const float* W2 = (const float*)d_in[4];
  const float* b2 = (const float*)d_in[5];
  const float* W3 = (const float*)d_in[6];
  const float* b3 = (const float*)d_in[7];
  float* out = (float*)d_out;

  char* ws = (char*)d_ws;
  const size_t SM = 16384;
  float* nsqA = (float*)(ws + 0 * SM);
  float* nsqB = (float*)(ws + 1 * SM);
  unsigned* maxA1u = (unsigned*)(ws + 2 * SM);
  unsigned* maxBu1 = (unsigned*)(ws + 3 * SM);
  unsigned* maxBu2 = (unsigned*)(ws + 4 * SM);
  float* maxA2 = (float*)(ws + 5 * SM);
  char* p = ws + 6 * SM;
  float* corr = (float*)p;                   p += (size_t)4 * 1024 * 1024 * 4;
  unsigned short* mm1h = (unsigned short*)p; p += (size_t)4 * 1024 * 1024 * 2;
  unsigned short* fAt = (unsigned short*)p;  p += (size_t)4 * 1024 * 1024 * 2;
  unsigned short* fBt = (unsigned short*)p;  p += (size_t)4 * 1024 * 1024 * 2;
  unsigned short* Wf = (unsigned short*)p;   p += 72 * 512 * 2;
  unsigned* w3p = (unsigned*)p;              p += 2 * 5 * 81 * 4 + 256;

  size_t fixed = (size_t)(p - ws);
  size_t perb = 4ull * 20971520ull;
  int NB = 4;
  while (NB > 1 && fixed + perb * (size_t)NB > ws_size) NB >>= 1;
  unsigned short* t1A = (unsigned short*)p;  p += (size_t)NB * 10 * 1024 * 1024 * 2;
  unsigned short* t1B = (unsigned short*)p;  p += (size_t)NB * 10 * 1024 * 1024 * 2;
  unsigned* t2pA = (unsigned*)p;             p += (size_t)NB * 5 * 1024 * 1024 * 4;
  unsigned* t2pB = (unsigned*)p;

  nc_zero_u32<<<48, 256, 0, stream>>>(maxA1u, 12288);
  nc_wpack<<<73, 256, 0, stream>>>(W1, W2, W3, Wf, w3p);
  nc_prep<<<dim3(16, 16, 8), 256, 0, stream>>>(fA, fB, fAt, fBt);
  nc_norms16<<<dim3(16, 4, 2), 256, 0, stream>>>(fAt, fBt, nsqA, nsqB);
  nc_gemm16<<<dim3(16, 16, 4), 256, 0, stream>>>(fAt, fBt, nsqA, nsqB, corr, maxA1u, maxBu1);
  nc_mm_f16<<<4096, 256, 0, stream>>>(corr, maxA1u, maxBu1, mm1h);

  for (int b0 = 0; b0 < 4; b0 += NB) {
    nc_conv1ab_k<<<dim3(1024, 4, NB), 256, 0, stream>>>(mm1h, Wf, b1, t1A, t1B, b0);
    nc_conv2ab_k<<<dim3(1024, 4, 2 * NB), 512, 0, stream>>>(t1A, t1B, Wf, b2, t2pA, t2pB);
    nc_conv3a<<<dim3(1024, NB), 256, 0, stream>>>(t2pA, w3p + 0, b3, out, b0);
    nc_conv3b<<<dim3(1024, NB), 256, 0, stream>>>(t2pB, w3p + 405, b3, out, b0);
  }

  nc_rowmax<<<4096, 256, 0, stream>>>(out, maxA2);
  nc_colmax<<<dim3(4, 64, 4), 256, 0, stream>>>(out, maxBu2);
  nc_mm_f32<<<4096, 256, 0, stream>>>(out, maxA2, maxBu2, out);
}

// Round 14
// 987.457 us; speedup vs baseline: 1.0826x; 1.0826x over previous
//
#include <hip/hip_runtime.h>
#include <math.h>

typedef _Float16 half8 __attribute__((ext_vector_type(8)));
typedef _Float16 half4 __attribute__((ext_vector_type(4)));
typedef _Float16 half2t __attribute__((ext_vector_type(2)));
typedef float floatx4 __attribute__((ext_vector_type(4)));

#if __has_builtin(__builtin_amdgcn_mfma_f32_16x16x16f16)
#define HAVE_MFMA16 1
#define MFMA_K16(a, b, c) __builtin_amdgcn_mfma_f32_16x16x16f16(a, b, c, 0, 0, 0)
#elif __has_builtin(__builtin_amdgcn_mfma_f32_16x16x16_f16)
#define HAVE_MFMA16 1
#define MFMA_K16(a, b, c) __builtin_amdgcn_mfma_f32_16x16x16_f16(a, b, c, 0, 0, 0)
#else
#define HAVE_MFMA16 0
#endif

static __device__ __forceinline__ unsigned f2o(float f) {
  unsigned b = __float_as_uint(f);
  return (b & 0x80000000u) ? ~b : (b | 0x80000000u);
}
static __device__ __forceinline__ float o2f(unsigned u) {
  return __uint_as_float((u & 0x80000000u) ? (u & 0x7fffffffu) : ~u);
}
static __device__ __forceinline__ unsigned pack2(float a, float b) {
  _Float16 ha = (_Float16)a, hb = (_Float16)b;
  unsigned short ua = __builtin_bit_cast(unsigned short, ha);
  unsigned short ub = __builtin_bit_cast(unsigned short, hb);
  return (unsigned)ua | ((unsigned)ub << 16);
}
static __device__ __forceinline__ float dot2acc(unsigned x, unsigned w, float acc) {
  half2t xh = __builtin_bit_cast(half2t, x);
  half2t wh = __builtin_bit_cast(half2t, w);
#if __has_builtin(__builtin_amdgcn_fdot2)
  return __builtin_amdgcn_fdot2(xh, wh, acc, false);
#else
  return fmaf((float)xh[0], (float)wh[0], fmaf((float)xh[1], (float)wh[1], acc));
#endif
}

__global__ void nc_zero_u32(unsigned* __restrict__ p, int n) {
  int i = blockIdx.x * blockDim.x + threadIdx.x;
  if (i < n) p[i] = 0u;
}

// ---------- prep: cast f32 [c][pos] -> f16 transposed [pos][c] ----------
__global__ __launch_bounds__(256) void nc_prep(const float* __restrict__ fA,
                                               const float* __restrict__ fB,
                                               unsigned short* __restrict__ fAt,
                                               unsigned short* __restrict__ fBt) {
  __shared__ float tile[64][65];
  int pt = blockIdx.x, ct = blockIdx.y, z = blockIdx.z;
  int b = z & 3, f = z >> 2;
  const float* src = (f ? fB : fA) + ((size_t)b << 20);
  unsigned short* dst = (f ? fBt : fAt) + ((size_t)b << 20);
  int p0 = pt << 6, c0 = ct << 6;
  int tid = threadIdx.x;
  int pcol = tid & 63, crow4 = tid >> 6;
#pragma unroll
  for (int it = 0; it < 16; ++it) {
    int c = (it << 2) + crow4;
    tile[c][pcol] = src[((size_t)(c0 + c) << 10) + p0 + pcol];
  }
  __syncthreads();
#pragma unroll
  for (int pass = 0; pass < 2; ++pass) {
    int u = tid + (pass << 8);
    int pr = u >> 3, c8 = (u & 7) << 3;
    unsigned short h[8];
#pragma unroll
    for (int e = 0; e < 8; ++e) {
      _Float16 v = (_Float16)tile[c8 + e][pr];
      h[e] = __builtin_bit_cast(unsigned short, v);
    }
    uint4 w;
    w.x = (unsigned)h[0] | ((unsigned)h[1] << 16);
    w.y = (unsigned)h[2] | ((unsigned)h[3] << 16);
    w.z = (unsigned)h[4] | ((unsigned)h[5] << 16);
    w.w = (unsigned)h[6] | ((unsigned)h[7] << 16);
    *(uint4*)&dst[((size_t)(p0 + pr) << 10) + c0 + c8] = w;
  }
}

// ---------- norm^2 per position ----------
__global__ __launch_bounds__(256) void nc_norms16(const unsigned short* __restrict__ fAt,
                                                  const unsigned short* __restrict__ fBt,
                                                  float* __restrict__ nsqA,
                                                  float* __restrict__ nsqB) {
  int b = blockIdx.y, f = blockIdx.z;
  const unsigned short* src = (f ? fBt : fAt) + ((size_t)b << 20);
  float* nsq = (f ? nsqB : nsqA) + (b << 10);
  int tid = threadIdx.x;
  int g = tid & 3, pos = (blockIdx.x << 6) + (tid >> 2);
  const unsigned short* row = src + ((size_t)pos << 10) + (g << 3);
  float s = 0.f;
#pragma unroll
  for (int i = 0; i < 32; ++i) {
    uint4 v = *(const uint4*)(row + (i << 5));
    const unsigned short* hp = (const unsigned short*)&v;
#pragma unroll
    for (int e = 0; e < 8; ++e) {
      float x = (float)__builtin_bit_cast(_Float16, hp[e]);
      s = fmaf(x, x, s);
    }
  }
  s += __shfl_xor(s, 1);
  s += __shfl_xor(s, 2);
  if (g == 0) nsq[pos] = s;
}

// ---------- correlation GEMM + fused row/col max; f16 corr out ----------
__global__ __launch_bounds__(256) void nc_gemm16(
    const unsigned short* __restrict__ fAt, const unsigned short* __restrict__ fBt,
    const float* __restrict__ nsqA, const float* __restrict__ nsqB,
    unsigned short* __restrict__ C16, unsigned* __restrict__ maxA1u,
    unsigned* __restrict__ maxBu1) {
  __shared__ unsigned short Ald[64 * 72];
  __shared__ unsigned short Bld[64 * 72];
  int q0 = blockIdx.x << 6, p0 = blockIdx.y << 6, b = blockIdx.z;
  const unsigned short* Ab = fAt + ((size_t)b << 20);
  const unsigned short* Bb = fBt + ((size_t)b << 20);
  int tid = threadIdx.x;
  int lane = tid & 63, w = tid >> 6;
  int ncol = lane & 15, g4 = lane >> 4;
  floatx4 acc[4];
#pragma unroll
  for (int t = 0; t < 4; ++t) acc[t] = (floatx4){0.f, 0.f, 0.f, 0.f};

  for (int k0 = 0; k0 < 1024; k0 += 64) {
    __syncthreads();
#pragma unroll
    for (int pass = 0; pass < 2; ++pass) {
      int u = tid + (pass << 8);
      int pr = u >> 3, c8 = (u & 7) << 3;
      *(uint4*)&Ald[pr * 72 + c8] = *(const uint4*)&Ab[((size_t)(p0 + pr) << 10) + k0 + c8];
      *(uint4*)&Bld[pr * 72 + c8] = *(const uint4*)&Bb[((size_t)(q0 + pr) << 10) + k0 + c8];
    }
    __syncthreads();
#pragma unroll
    for (int ch = 0; ch < 2; ++ch) {
      half8 af = *(const half8*)&Ald[(w * 16 + ncol) * 72 + (ch << 5) + (g4 << 3)];
#pragma unroll
      for (int t = 0; t < 4; ++t) {
        half8 bf = *(const half8*)&Bld[(t * 16 + ncol) * 72 + (ch << 5) + (g4 << 3)];
        acc[t] = __builtin_amdgcn_mfma_f32_16x16x32_f16(af, bf, acc[t], 0, 0, 0);
      }
    }
  }

  float na[4], nb[4];
#pragma unroll
  for (int r = 0; r < 4; ++r) na[r] = nsqA[(b << 10) + p0 + w * 16 + (g4 << 2) + r] + 1e-6f;
#pragma unroll
  for (int t = 0; t < 4; ++t) nb[t] = nsqB[(b << 10) + q0 + t * 16 + ncol] + 1e-6f;

  float rm[4] = {-INFINITY, -INFINITY, -INFINITY, -INFINITY};
  float cm[4];
#pragma unroll
  for (int t = 0; t < 4; ++t) {
    float colm = -INFINITY;
#pragma unroll
    for (int r = 0; r < 4; ++r) {
      float val = acc[t][r] * rsqrtf(na[r] * nb[t]);
      size_t o = ((size_t)b << 20) + ((size_t)(p0 + w * 16 + (g4 << 2) + r) << 10) +
                 q0 + t * 16 + ncol;
      _Float16 h = (_Float16)val;
      C16[o] = __builtin_bit_cast(unsigned short, h);
      rm[r] = fmaxf(rm[r], val);
      colm = fmaxf(colm, val);
    }
    cm[t] = colm;
  }
#pragma unroll
  for (int d = 1; d <= 8; d <<= 1)
#pragma unroll
    for (int r = 0; r < 4; ++r) rm[r] = fmaxf(rm[r], __shfl_xor(rm[r], d));
  if (ncol == 0) {
#pragma unroll
    for (int r = 0; r < 4; ++r)
      atomicMax(&maxA1u[(b << 10) + p0 + w * 16 + (g4 << 2) + r], f2o(rm[r]));
  }
#pragma unroll
  for (int d = 16; d <= 32; d <<= 1)
#pragma unroll
    for (int t = 0; t < 4; ++t) cm[t] = fmaxf(cm[t], __shfl_xor(cm[t], d));
  if (g4 == 0) {
#pragma unroll
    for (int t = 0; t < 4; ++t)
      atomicMax(&maxBu1[(b << 10) + q0 + t * 16 + ncol], f2o(cm[t]));
  }
}

// ---------- row / col max (fp32, final pass) ----------
__global__ __launch_bounds__(256) void nc_rowmax(const float* __restrict__ X,
                                                 float* __restrict__ rmax) {
  int row = blockIdx.x;
  const float* x = X + ((size_t)row << 10);
  int tid = threadIdx.x;
  float m = fmaxf(fmaxf(x[tid], x[tid + 256]), fmaxf(x[tid + 512], x[tid + 768]));
  __shared__ float red[256];
  red[tid] = m;
  __syncthreads();
  for (int s = 128; s > 0; s >>= 1) {
    if (tid < s) red[tid] = fmaxf(red[tid], red[tid + s]);
    __syncthreads();
  }
  if (tid == 0) rmax[row] = red[0];
}

__global__ __launch_bounds__(256) void nc_colmax(const float* __restrict__ X,
                                                 unsigned* __restrict__ cmaxu) {
  int b = blockIdx.z;
  int q = (blockIdx.x << 8) + threadIdx.x;
  int p0 = blockIdx.y << 4;
  const float* x = X + ((size_t)b << 20) + ((size_t)p0 << 10) + q;
  float m = -INFINITY;
#pragma unroll
  for (int r = 0; r < 16; ++r) m = fmaxf(m, x[(size_t)r << 10]);
  atomicMax(&cmaxu[(b << 10) + q], f2o(m));
}

// ---------- mutual matching ----------
__global__ __launch_bounds__(256) void nc_mm_f32(const float* __restrict__ X,
                                                 const float* __restrict__ rmax,
                                                 const unsigned* __restrict__ cmaxu,
                                                 float* __restrict__ Y) {
  size_t i4 = (size_t)blockIdx.x * 256 + threadIdx.x;
  size_t base = i4 << 2;
  float4 x = *(const float4*)&X[base];
  float ma = rmax[base >> 10] + 1e-5f;
  const unsigned* cm = &cmaxu[((base >> 20) << 10) + (base & 1023)];
  float4 y;
  y.x = x.x * x.x * x.x / (ma * (o2f(cm[0]) + 1e-5f));
  y.y = x.y * x.y * x.y / (ma * (o2f(cm[1]) + 1e-5f));
  y.z = x.z * x.z * x.z / (ma * (o2f(cm[2]) + 1e-5f));
  y.w = x.w * x.w * x.w / (ma * (o2f(cm[3]) + 1e-5f));
  *(float4*)&Y[base] = y;
}

// reads f16 corr
__global__ __launch_bounds__(256) void nc_mm_f16(const unsigned short* __restrict__ X16,
                                                 const unsigned* __restrict__ rmaxu,
                                                 const unsigned* __restrict__ cmaxu,
                                                 unsigned short* __restrict__ Y16) {
  size_t i4 = (size_t)blockIdx.x * 256 + threadIdx.x;
  size_t base = i4 << 2;
  ushort4 xv = *(const ushort4*)&X16[base];
  float x0 = (float)__builtin_bit_cast(_Float16, xv.x);
  float x1 = (float)__builtin_bit_cast(_Float16, xv.y);
  float x2 = (float)__builtin_bit_cast(_Float16, xv.z);
  float x3 = (float)__builtin_bit_cast(_Float16, xv.w);
  float ma = o2f(rmaxu[base >> 10]) + 1e-5f;
  const unsigned* cm = &cmaxu[((base >> 20) << 10) + (base & 1023)];
  float y0 = x0 * x0 * x0 / (ma * (o2f(cm[0]) + 1e-5f));
  float y1 = x1 * x1 * x1 / (ma * (o2f(cm[1]) + 1e-5f));
  float y2 = x2 * x2 * x2 / (ma * (o2f(cm[2]) + 1e-5f));
  float y3 = x3 * x3 * x3 / (ma * (o2f(cm[3]) + 1e-5f));
  unsigned* dst = (unsigned*)&Y16[base];
  dst[0] = pack2(y0, y1);
  dst[1] = pack2(y2, y3);
}

// ---------- weight prepack: Wf (K=32 frags), w3p, Wf1 (K=16 conv1 frags) ----------
__global__ void nc_wpack(const float* __restrict__ W1, const float* __restrict__ W2,
                         const float* __restrict__ W3,
                         unsigned short* __restrict__ Wf, unsigned* __restrict__ w3p,
                         unsigned short* __restrict__ Wf1) {
  int f = blockIdx.x;
  int t = threadIdx.x;
  if (f < 72) {
    int v, chunk, tap, CI;
    const float* W;
    if (f < 18) { v = f / 9; tap = f % 9; chunk = 0; CI = 1; W = W1; }
    else { int g = f - 18; v = g / 27; g %= 27; chunk = g / 9; tap = g % 9; CI = 10; W = W2; }
    for (int e = t; e < 512; e += 256) {
      int lane = e >> 3, j = e & 7;
      int co = lane & 15;
      int k = ((lane >> 4) << 3) + j;
      int cip = chunk * 32 + k;
      float val = 0.f;
      if (co < 10 && cip < CI * 9) {
        int ci = cip / 9, r = cip % 9;
        int widx = v ? (tap * 9 + r) : (r * 9 + tap);
        val = W[(co * CI + ci) * 81 + widx];
      }
      _Float16 h = (_Float16)val;
      Wf[f * 512 + e] = __builtin_bit_cast(unsigned short, h);
    }
  } else if (f == 72) {
    for (int e = t; e < 2 * 5 * 81; e += 256) {
      int v = e / 405;
      int rem = e - v * 405;
      int p = rem / 81;
      int t81 = rem - p * 81;
      int r = t81 / 9, ab = t81 - r * 9;
      int widx = v ? (ab * 9 + r) : (r * 9 + ab);
      w3p[e] = pack2(W3[(2 * p) * 81 + widx], W3[(2 * p + 1) * 81 + widx]);
    }
  } else {
    // conv1 K=16 frags: f1 = f-73 in 0..17 (v = f1/9, tap = f1%9); 256 halves.
    int f1 = f - 73;
    int v = f1 / 9, tap = f1 % 9;
    if (t < 256) {
      int lane = t >> 2, j = t & 3;
      int co = lane & 15;
      int k = ((lane >> 4) << 2) + j;  // 0..15
      float val = 0.f;
      if (co < 10 && k < 9) {
        int widx = v ? (tap * 9 + k) : (k * 9 + tap);
        val = W1[co * 81 + widx];
      }
      _Float16 h = (_Float16)val;
      Wf1[f1 * 256 + t] = __builtin_bit_cast(unsigned short, h);
    }
  }
}

// ---------- conv1, both branches, K=16 MFMA; grid (1024, 4, NB) ----------
__global__ __launch_bounds__(256, 5) void nc_conv1ab_k(
    const unsigned short* __restrict__ xin, const unsigned short* __restrict__ Wf,
    const unsigned short* __restrict__ Wf1, const float* __restrict__ bias,
    unsigned short* __restrict__ t1A, unsigned short* __restrict__ t1B, int b_base) {
  __shared__ unsigned short xs[360 * 40];
  int bx = blockIdx.x, qt = blockIdx.y;
  int bl = blockIdx.z;
  int b = b_base + bl;
  unsigned short* t1Ab = t1A + ((size_t)bl * 10 << 20);
  unsigned short* t1Bb = t1B + ((size_t)bl * 10 << 20);
  int ij = ((bx & 7) << 7) + (bx >> 3);
  int i = ij >> 5, j = ij & 31;
  int tid = threadIdx.x;
  int lane = tid & 63, w = tid >> 6;
  int ncol = lane & 15, g4 = lane >> 4;
  int kp = tid & 15, colg = (tid >> 4) & 7, rowb = tid >> 7;

  if (tid < 80) {
    int rr = tid >> 3;
    int e = tid & 7;
    int pos = rr * 36 + ((e >> 2) ? 33 : 0);
    half8 z = {};
    *(half8*)((char*)xs + pos * 80 + (e & 3) * 16) = z;
  }

  const unsigned short* p0 = nullptr;
  const unsigned short* p1 = nullptr;
  {
    int cip0 = kp << 1;
    if (cip0 < 9) {
      int ii = i + cip0 / 3 - 1, jj = j + cip0 % 3 - 1;
      if ((unsigned)ii < 32u && (unsigned)jj < 32u)
        p0 = xin + ((size_t)b << 20) + ((ii * 32 + jj) << 10);
    }
    int cip1 = cip0 + 1;
    if (cip1 < 9) {
      int ii = i + cip1 / 3 - 1, jj = j + cip1 % 3 - 1;
      if ((unsigned)ii < 32u && (unsigned)jj < 32u)
        p1 = xin + ((size_t)b << 20) + ((ii * 32 + jj) << 10);
    }
  }
  ushort4 a0[5], a1[5];
#pragma unroll
  for (int it = 0; it < 5; ++it) {
    int row_g = (qt << 3) - 1 + rowb + 2 * it;
    bool rv = (unsigned)row_g < 32u;
    int goff = (row_g << 5) + (colg << 2);
    ushort4 z = {0, 0, 0, 0};
    a0[it] = z; a1[it] = z;
    if (rv && p0) a0[it] = *(const ushort4*)(p0 + goff);
    if (rv && p1) a1[it] = *(const ushort4*)(p1 + goff);
  }
  __syncthreads();
#pragma unroll
  for (int it = 0; it < 5; ++it) {
    int row = rowb + 2 * it;
    unsigned* dstw = (unsigned*)xs + (row * 36 + 1 + (colg << 2)) * 20 + kp;
    dstw[0]  = (unsigned)a0[it].x | ((unsigned)a1[it].x << 16);
    dstw[20] = (unsigned)a0[it].y | ((unsigned)a1[it].y << 16);
    dstw[40] = (unsigned)a0[it].z | ((unsigned)a1[it].z << 16);
    dstw[60] = (unsigned)a0[it].w | ((unsigned)a1[it].w << 16);
  }
  __syncthreads();

  floatx4 accA[4], accB[4];
#pragma unroll
  for (int q = 0; q < 4; ++q) {
    accA[q] = (floatx4){0.f, 0.f, 0.f, 0.f};
    accB[q] = (floatx4){0.f, 0.f, 0.f, 0.f};
  }

#if HAVE_MFMA16
  int rbase16[4];
#pragma unroll
  for (int q = 0; q < 4; ++q) {
    int n0 = (((w << 2) + q) << 4);
    rbase16[q] = ((n0 >> 5) * 36 + (n0 & 31) + ncol) * 80 + (g4 << 3);
  }
  const unsigned short* wfp1 = Wf1 + (lane << 2);
#pragma unroll
  for (int tap = 0; tap < 9; ++tap) {
    half4 afA = *(const half4*)(wfp1 + tap * 256);
    half4 afB = *(const half4*)(wfp1 + (9 + tap) * 256);
    const int off = ((tap / 3) * 36 + (tap % 3)) * 80;
#pragma unroll
    for (int q = 0; q < 4; ++q) {
      half4 bv = *(const half4*)((const char*)xs + rbase16[q] + off);
      accA[q] = MFMA_K16(afA, bv, accA[q]);
      accB[q] = MFMA_K16(afB, bv, accB[q]);
    }
  }
#else
  int rbase[4];
#pragma unroll
  for (int q = 0; q < 4; ++q) {
    int n0 = (((w << 2) + q) << 4);
    rbase[q] = ((n0 >> 5) * 36 + (n0 & 31) + ncol) * 80 + (g4 << 4);
  }
  const unsigned short* wfp = Wf + (lane << 3);
#pragma unroll
  for (int tap = 0; tap < 9; ++tap) {
    half8 afA = *(const half8*)(wfp + tap * 512);
    half8 afB = *(const half8*)(wfp + (9 + tap) * 512);
    const int off = ((tap / 3) * 36 + (tap % 3)) * 80;
#pragma unroll
    for (int q = 0; q < 4; ++q) {
      half8 bv = *(const half8*)((const char*)xs + rbase[q] + off);
      accA[q] = __builtin_amdgcn_mfma_f32_16x16x32_f16(afA, bv, accA[q], 0, 0, 0);
      accB[q] = __builtin_amdgcn_mfma_f32_16x16x32_f16(afB, bv, accB[q], 0, 0, 0);
    }
  }
#endif

#pragma unroll
  for (int q = 0; q < 4; ++q) {
    int ng = (qt << 8) + (((w << 2) + q) << 4) + ncol;
#pragma unroll
    for (int r = 0; r < 4; ++r) {
      int co = (g4 << 2) + r;
      if (co < 10) {
        size_t oidx = ((size_t)co << 20) + ((size_t)ij << 10) + ng;
        float vA = fmaxf(accA[q][r] + bias[co], 0.f);
        float vB = fmaxf(accB[q][r] + bias[co], 0.f);
        _Float16 hA = (_Float16)vA, hB = (_Float16)vB;
        t1Ab[oidx] = __builtin_bit_cast(unsigned short, hA);
        t1Bb[oidx] = __builtin_bit_cast(unsigned short, hB);
      }
    }
  }
}

// ---------- conv2 (10->10), R11 body; grid (1024, 4, 2*NB): z = br | bl<<1 ----------
__global__ __launch_bounds__(256, 5) void nc_conv2ab_k(
    const unsigned short* __restrict__ t1A, const unsigned short* __restrict__ t1B,
    const unsigned short* __restrict__ Wf, const float* __restrict__ bias,
    unsigned* __restrict__ t2pA, unsigned* __restrict__ t2pB) {
  constexpr int NCH = 3;
  __shared__ unsigned short xs[360 * 40];
  int z = blockIdx.z;
  int br = z & 1, bl = z >> 1;
  const unsigned short* xin = (br ? t1B : t1A) + ((size_t)bl * 10 << 20);
  const unsigned short* Wfz = Wf + (size_t)(18 + br * 27) * 512;
  unsigned* t2p = (br ? t2pB : t2pA) + ((size_t)bl * 5 << 20);
  int bx = blockIdx.x, qt = blockIdx.y;
  int ij = ((bx & 7) << 7) + (bx >> 3);
  int i = ij >> 5, j = ij & 31;
  int tid = threadIdx.x;
  int lane = tid & 63, w = tid >> 6;
  int ncol = lane & 15, g4 = lane >> 4;
  int kp = tid & 15, colg = (tid >> 4) & 7, rowb = tid >> 7;

  if (tid < 80) {
    int rr = tid >> 3;
    int e = tid & 7;
    int pos = rr * 36 + ((e >> 2) ? 33 : 0);
    half8 zz = {};
    *(half8*)((char*)xs + pos * 80 + (e & 3) * 16) = zz;
  }

  int rbase[4];
#pragma unroll
  for (int q = 0; q < 4; ++q) {
    int n0 = (((w << 2) + q) << 4);
    rbase[q] = ((n0 >> 5) * 36 + (n0 & 31) + ncol) * 80 + (g4 << 4);
  }

  floatx4 acc[4];
#pragma unroll
  for (int q = 0; q < 4; ++q) acc[q] = (floatx4){0.f, 0.f, 0.f, 0.f};

  ushort4 a0[5], a1[5];
  auto PREF = [&](int ch) {
    int cip0 = (ch << 5) + (kp << 1);
    const unsigned short* p0 = nullptr;
    const unsigned short* p1 = nullptr;
    if (cip0 < 90) {
      int ci = cip0 / 9, r9 = cip0 - ci * 9;
      int ii = i + r9 / 3 - 1, jj = j + r9 % 3 - 1;
      if ((unsigned)ii < 32u && (unsigned)jj < 32u)
        p0 = xin + ((size_t)ci << 20) + ((ii * 32 + jj) << 10);
    }
    int cip1 = cip0 + 1;
    if (cip1 < 90) {
      int ci = cip1 / 9, r9 = cip1 - ci * 9;
      int ii = i + r9 / 3 - 1, jj = j + r9 % 3 - 1;
      if ((unsigned)ii < 32u && (unsigned)jj < 32u)
        p1 = xin + ((size_t)ci << 20) + ((ii * 32 + jj) << 10);
    }
#pragma unroll
    for (int it = 0; it < 5; ++it) {
      int row_g = (qt << 3) - 1 + rowb + 2 * it;
      bool rv = (unsigned)row_g < 32u;
      int goff = (row_g << 5) + (colg << 2);
      ushort4 zv = {0, 0, 0, 0};
      a0[it] = zv; a1[it] = zv;
      if (rv && p0) a0[it] = *(const ushort4*)(p0 + goff);
      if (rv && p1) a1[it] = *(const ushort4*)(p1 + goff);
    }
  };

  PREF(0);
  for (int ch = 0; ch < NCH; ++ch) {
    __syncthreads();
#pragma unroll
    for (int it = 0; it < 5; ++it) {
      int row = rowb + 2 * it;
      unsigned* dstw = (unsigned*)xs + (row * 36 + 1 + (colg << 2)) * 20 + kp;
      dstw[0]  = (unsigned)a0[it].x | ((unsigned)a1[it].x << 16);
      dstw[20] = (unsigned)a0[it].y | ((unsigned)a1[it].y << 16);
      dstw[40] = (unsigned)a0[it].z | ((unsigned)a1[it].z << 16);
      dstw[60] = (unsigned)a0[it].w | ((unsigned)a1[it].w << 16);
    }
    __syncthreads();
    if (ch + 1 < NCH) PREF(ch + 1);

    const unsigned short* wfp = Wfz + (size_t)(ch * 9) * 512 + (lane << 3);
#pragma unroll
    for (int tap = 0; tap < 9; ++tap) {
      half8 af = *(const half8*)(wfp + tap * 512);
      const int off = ((tap / 3) * 36 + (tap % 3)) * 80;
#pragma unroll
      for (int q = 0; q < 4; ++q) {
        half8 bv = *(const half8*)((const char*)xs + rbase[q] + off);
        acc[q] = __builtin_amdgcn_mfma_f32_16x16x32_f16(af, bv, acc[q], 0, 0, 0);
      }
    }
  }

#pragma unroll
  for (int q = 0; q < 4; ++q) {
    int ng = (qt << 8) + (((w << 2) + q) << 4) + ncol;
    int c0 = g4 << 2;
    float v0 = fmaxf(acc[q][0] + (c0 + 0 < 10 ? bias[c0 + 0] : 0.f), 0.f);
    float v1 = fmaxf(acc[q][1] + (c0 + 1 < 10 ? bias[c0 + 1] : 0.f), 0.f);
    float v2 = fmaxf(acc[q][2] + (c0 + 2 < 10 ? bias[c0 + 2] : 0.f), 0.f);
    float v3 = fmaxf(acc[q][3] + (c0 + 3 < 10 ? bias[c0 + 3] : 0.f), 0.f);
    int p0 = g4 << 1;
    if (p0 < 5)
      t2p[((size_t)p0 << 20) + ((size_t)ij << 10) + ng] = pack2(v0, v1);
    if (p0 + 1 < 5)
      t2p[((size_t)(p0 + 1) << 20) + ((size_t)ij << 10) + ng] = pack2(v2, v3);
  }
}

// ---------- conv3 (10->1), DPP halo exchange; grid (1024, NB) ----------
template <bool ACCUM>
static __device__ __forceinline__ void nc_conv3_body(
    const unsigned* __restrict__ t2p, const unsigned* __restrict__ w3p,
    const float* __restrict__ b3, float* __restrict__ yout, int b_base) {
  __shared__ unsigned xs2[5][33 * 32];
  int bx = blockIdx.x;
  int bl = blockIdx.y;
  int b = b_base + bl;
  const unsigned* t2b = t2p + ((size_t)bl * 5 << 20);
  int ij = ((bx & 7) << 7) + (bx >> 3);
  int i = ij >> 5, j = ij & 31;
  int tid = threadIdx.x;
  int k = tid >> 3, l4 = (tid & 7) << 2;
  float acc[4] = {0.f, 0.f, 0.f, 0.f};

  for (int di = -1; di <= 1; ++di) {
    int ii = i + di;
    for (int dj = -1; dj <= 1; ++dj) {
      int jj = j + dj;
      bool pv = ((unsigned)ii < 32u) && ((unsigned)jj < 32u);
      if (!pv) continue;
      __syncthreads();
#pragma unroll
      for (int p = 0; p < 5; ++p) {
#pragma unroll
        for (int s = 0; s < 4; ++s) {
          int pos = (s << 8) + tid;
          unsigned v = t2b[((size_t)p << 20) + ((size_t)(ii * 32 + jj) << 10) + pos];
          xs2[p][(pos >> 5) * 33 + (pos & 31)] = v;
        }
      }
      __syncthreads();
      int r9 = (di + 1) * 3 + (dj + 1);
#pragma unroll
      for (int p = 0; p < 5; ++p) {
        unsigned vv[3][6];
#pragma unroll
        for (int a = 0; a < 3; ++a) {
          int rr = k + a - 1;
          bool rv = (unsigned)rr < 32u;
          unsigned c0 = rv ? xs2[p][rr * 33 + l4 + 0] : 0u;
          unsigned c1 = rv ? xs2[p][rr * 33 + l4 + 1] : 0u;
          unsigned c2 = rv ? xs2[p][rr * 33 + l4 + 2] : 0u;
          unsigned c3 = rv ? xs2[p][rr * 33 + l4 + 3] : 0u;
          int Ld = __builtin_amdgcn_update_dpp(0, (int)c3, 0x111, 0xf, 0xf, true);
          int Rd = __builtin_amdgcn_update_dpp(0, (int)c0, 0x101, 0xf, 0xf, true);
          vv[a][0] = (l4 == 0) ? 0u : (unsigned)Ld;
          vv[a][1] = c0; vv[a][2] = c1; vv[a][3] = c2; vv[a][4] = c3;
          vv[a][5] = (l4 == 28) ? 0u : (unsigned)Rd;
        }
#pragma unroll
        for (int a = 0; a < 3; ++a)
#pragma unroll
          for (int bc = 0; bc < 3; ++bc) {
            unsigned wp = w3p[p * 81 + r9 * 9 + a * 3 + bc];
#pragma unroll
            for (int r = 0; r < 4; ++r) acc[r] = dot2acc(vv[a][r + bc], wp, acc[r]);
          }
      }
    }
  }
  float bb = b3[0];
  size_t o = ((size_t)b << 20) + ((size_t)ij << 10) + (k << 5) + l4;
  float4 out4;
  out4.x = fmaxf(acc[0] + bb, 0.f);
  out4.y = fmaxf(acc[1] + bb, 0.f);
  out4.z = fmaxf(acc[2] + bb, 0.f);
  out4.w = fmaxf(acc[3] + bb, 0.f);
  if (ACCUM) {
    float4 prev = *(const float4*)&yout[o];
    out4.x += prev.x; out4.y += prev.y; out4.z += prev.z; out4.w += prev.w;
  }
  *(float4*)&yout[o] = out4;
}

__global__ __launch_bounds__(256) void nc_conv3a(
    const unsigned* __restrict__ t2p, const unsigned* __restrict__ w3p,
    const float* __restrict__ b3, float* __restrict__ yout, int b_base) {
  nc_conv3_body<false>(t2p, w3p, b3, yout, b_base);
}
__global__ __launch_bounds__(256) void nc_conv3b(
    const unsigned* __restrict__ t2p, const unsigned* __restrict__ w3p,
    const float* __restrict__ b3, float* __restrict__ yout, int b_base) {
  nc_conv3_body<true>(t2p, w3p, b3, yout, b_base);
}

extern "C" void kernel_launch(void* const* d_in, const int* in_sizes, int n_in,
                              void* d_out, int out_size, void* d_ws, size_t ws_size,
                              hipStream_t stream) {
  const float* fA = (const float*)d_in[0];
  const float* fB = (const float*)d_in[1];
  const float* W1 = (const float*)d_in[2];
  const float* b1 = (const float*)d_in[3];
  const float* W2 = (const float*)d_in[4];
  const float* b2 = (const float*)d_in[5];
  const float* W3 = (const float*)d_in[6];
  const float* b3 = (const float*)d_in[7];
  float* out = (float*)d_out;

  char* ws = (char*)d_ws;
  const size_t SM = 16384;
  float* nsqA = (float*)(ws + 0 * SM);
  float* nsqB = (float*)(ws + 1 * SM);
  unsigned* maxA1u = (unsigned*)(ws + 2 * SM);
  unsigned* maxBu1 = (unsigned*)(ws + 3 * SM);
  unsigned* maxBu2 = (unsigned*)(ws + 4 * SM);
  float* maxA2 = (float*)(ws + 5 * SM);
  char* p = ws + 6 * SM;
  unsigned short* corrh = (unsigned short*)p;  p += (size_t)4 * 1024 * 1024 * 2;  // 8.4 MB
  unsigned short* mm1h = (unsigned short*)p;   p += (size_t)4 * 1024 * 1024 * 2;  // 8.4 MB
  unsigned short* fAt = (unsigned short*)p;    p += (size_t)4 * 1024 * 1024 * 2;
  unsigned short* fBt = (unsigned short*)p;    p += (size_t)4 * 1024 * 1024 * 2;
  unsigned short* Wf = (unsigned short*)p;     p += 72 * 512 * 2;
  unsigned short* Wf1 = (unsigned short*)p;    p += 18 * 256 * 2;
  unsigned* w3p = (unsigned*)p;                p += 2 * 5 * 81 * 4 + 256;

  size_t fixed = (size_t)(p - ws);
  size_t perb = 4ull * 20971520ull;
  int NB = 4;
  while (NB > 1 && fixed + perb * (size_t)NB > ws_size) NB >>= 1;
  unsigned short* t1A = (unsigned short*)p;  p += (size_t)NB * 10 * 1024 * 1024 * 2;
  unsigned short* t1B = (unsigned short*)p;  p += (size_t)NB * 10 * 1024 * 1024 * 2;
  unsigned* t2pA = (unsigned*)p;             p += (size_t)NB * 5 * 1024 * 1024 * 4;
  unsigned* t2pB = (unsigned*)p;

  nc_zero_u32<<<48, 256, 0, stream>>>(maxA1u, 12288);
  nc_wpack<<<91, 256, 0, stream>>>(W1, W2, W3, Wf, w3p, Wf1);
  nc_prep<<<dim3(16, 16, 8), 256, 0, stream>>>(fA, fB, fAt, fBt);
  nc_norms16<<<dim3(16, 4, 2), 256, 0, stream>>>(fAt, fBt, nsqA, nsqB);
  nc_gemm16<<<dim3(16, 16, 4), 256, 0, stream>>>(fAt, fBt, nsqA, nsqB, corrh, maxA1u, maxBu1);
  nc_mm_f16<<<4096, 256, 0, stream>>>(corrh, maxA1u, maxBu1, mm1h);

  for (int b0 = 0; b0 < 4; b0 += NB) {
    nc_conv1ab_k<<<dim3(1024, 4, NB), 256, 0, stream>>>(mm1h, Wf, Wf1, b1, t1A, t1B, b0);
    nc_conv2ab_k<<<dim3(1024, 4, 2 * NB), 256, 0, stream>>>(t1A, t1B, Wf, b2, t2pA, t2pB);
    nc_conv3a<<<dim3(1024, NB), 256, 0, stream>>>(t2pA, w3p + 0, b3, out, b0);
    nc_conv3b<<<dim3(1024, NB), 256, 0, stream>>>(t2pB, w3p + 405, b3, out, b0);
  }

  nc_rowmax<<<4096, 256, 0, stream>>>(out, maxA2);
  nc_colmax<<<dim3(4, 64, 4), 256, 0, stream>>>(out, maxBu2);
  nc_mm_f32<<<4096, 256, 0, stream>>>(out, maxA2, maxBu2, out);
}